// Round 15
// baseline (199.744 us; speedup 1.0000x reference)
//
#include <hip/hip_runtime.h>
#include <math.h>

#define BB 8
#define NVV 2048
#define NPP 4096
#define DD 64
#define NQ (BB * NVV)     // 16384 vertex rows
#define QT32 (NQ / 32)    // 512 query tiles (32 rows each)
#define PT32 ((BB * NPP) / 32)  // 1024 pf tiles
#define NC1 4             // KNN1 chunks: 32 tiles (1024 keys) each
#define NC2 4             // KNN2 chunks: 16 tiles (512 keys) each

typedef __attribute__((ext_vector_type(8))) short short8;
typedef __attribute__((ext_vector_type(8))) unsigned short ushort8;
typedef __attribute__((ext_vector_type(16))) float f32x16;

// ws layout (float offsets), audited line-by-line (R10 lesson):
// vm      @0        (16384)
// inv_vf_s@16384    (16384)   = 16384/norm
// inv_pf_s@32768    (32768)
// flow    @65536    (65536)
// pc1     @131072   (32*16384 uints = 524288)
// pc2     @655360   (32*16384 uints = 524288)
// vfh     @1179648  (512 tiles * 2048 ushorts = 524288 floats)
// vfl     @1703936  (+524288)
// pfh     @2228224  (1024 tiles * 2048 ushorts = 1048576 floats)
// pfl     @3276800  (+1048576)
// end     @4325376  floats = 17.3 MB
// frag slot formula (A and B share it; shared k-permutation cancels in MFMA):
//   frag[tile][c][lane][j] = M[tile*32+(lane&31)][c*16+(lane>>5)*8+j]
//   addr = ((tile*4+c)*64+lane)*8 ushorts

__device__ __forceinline__ unsigned short bf16rn(float x) {
  unsigned u = __float_as_uint(x);
  return (unsigned short)((u + 0x7FFFu + ((u >> 16) & 1u)) >> 16);
}
__device__ __forceinline__ float bf2f(unsigned short h) {
  return __uint_as_float(((unsigned)h) << 16);
}

// Branchless sorted-ascending top-8 insert: 7x v_med3_u32 + 1x max.
__device__ __forceinline__ void net8(unsigned* a, unsigned v) {
#pragma unroll
  for (int k = 0; k < 7; k++) {
    unsigned r;
    asm("v_med3_u32 %0, %1, %2, %3" : "=v"(r) : "v"(v), "v"(a[k]), "v"(a[k + 1]));
    a[k] = r;
  }
  a[7] = a[7] > v ? a[7] : v;
}

__device__ __forceinline__ void ins8(float* tv, int* ti, float v, int id) {
  bool c1 = v > tv[1], c2 = v > tv[2], c3 = v > tv[3];
  bool c4 = v > tv[4], c5 = v > tv[5], c6 = v > tv[6], c7 = v > tv[7];
  tv[0] = c1 ? tv[1] : v;                ti[0] = c1 ? ti[1] : id;
  tv[1] = c2 ? tv[2] : (c1 ? v : tv[1]); ti[1] = c2 ? ti[2] : (c1 ? id : ti[1]);
  tv[2] = c3 ? tv[3] : (c2 ? v : tv[2]); ti[2] = c3 ? ti[3] : (c2 ? id : ti[2]);
  tv[3] = c4 ? tv[4] : (c3 ? v : tv[3]); ti[3] = c4 ? ti[4] : (c3 ? id : ti[3]);
  tv[4] = c5 ? tv[5] : (c4 ? v : tv[4]); ti[4] = c5 ? ti[5] : (c4 ? id : ti[4]);
  tv[5] = c6 ? tv[6] : (c5 ? v : tv[5]); ti[5] = c6 ? ti[6] : (c5 ? id : ti[5]);
  tv[6] = c7 ? tv[7] : (c6 ? v : tv[6]); ti[6] = c7 ? ti[7] : (c6 ? id : ti[6]);
  tv[7] = c7 ? v : tv[7];                ti[7] = c7 ? id : ti[7];
}

// ===== kernel 1: vm (blocks 0..7) + wave-per-32-row-tile norm+staging =====
// Lane l: row r=l&31, half h=l>>5 (cols h*32..h*32+31). Row sumsq via
// shfl_xor(32). Writes 4 frag slots (2 kchunks x 2 lane-halves) hi+lo.
__global__ __launch_bounds__(256) void k_prep(const float* __restrict__ logits,
                                              const float* __restrict__ vf,
                                              const float* __restrict__ pf,
                                              float* __restrict__ vm,
                                              float* __restrict__ inv_vf_s,
                                              float* __restrict__ inv_pf_s,
                                              unsigned short* __restrict__ vfh,
                                              unsigned short* __restrict__ vfl,
                                              unsigned short* __restrict__ pfh,
                                              unsigned short* __restrict__ pfl,
                                              float* __restrict__ out) {
  int bid = blockIdx.x, t = threadIdx.x;
  if (bid < BB) {
    int b = bid;
    __shared__ float smn[4], smx[4];
    float vals[8];
    float mn = 1e30f, mx = -1e30f;
#pragma unroll
    for (int i = 0; i < 8; i++) {
      float x = logits[b * NVV + t + i * 256];
      float s = 1.0f / (1.0f + expf(-x));
      vals[i] = s;
      mn = fminf(mn, s);
      mx = fmaxf(mx, s);
    }
    for (int o = 32; o; o >>= 1) {
      mn = fminf(mn, __shfl_xor(mn, o, 64));
      mx = fmaxf(mx, __shfl_xor(mx, o, 64));
    }
    int w = t >> 6;
    if ((t & 63) == 0) { smn[w] = mn; smx[w] = mx; }
    __syncthreads();
    mn = fminf(fminf(smn[0], smn[1]), fminf(smn[2], smn[3]));
    mx = fmaxf(fmaxf(smx[0], smx[1]), fmaxf(smx[2], smx[3]));
    float range = mx - mn;
#pragma unroll
    for (int i = 0; i < 8; i++) {
      float v = (vals[i] - mn) / range;
      int g = b * NVV + t + i * 256;
      vm[g] = v;
      out[g * 4 + 3] = v;
    }
  } else {
    // 4 tiles per block (one per wave); 1536 tiles; vf/pf split at 512
    int tile_g = (bid - BB) * 4 + (t >> 6);
    int lane = t & 63, r = lane & 31, h = lane >> 5;
    const float* src;
    unsigned short *dh, *dl;
    float* ginv;
    int tile;
    if (tile_g < QT32) { tile = tile_g; src = vf; dh = vfh; dl = vfl; ginv = inv_vf_s; }
    else { tile = tile_g - QT32; src = pf; dh = pfh; dl = pfl; ginv = inv_pf_s; }
    int row = tile * 32 + r;
    const float* rp = src + (size_t)row * DD + h * 32;
    float xs[32];
#pragma unroll
    for (int c4 = 0; c4 < 8; c4++) {
      float4 v = *(const float4*)(rp + c4 * 4);
      xs[c4 * 4 + 0] = v.x; xs[c4 * 4 + 1] = v.y;
      xs[c4 * 4 + 2] = v.z; xs[c4 * 4 + 3] = v.w;
    }
    float ss = 0.f;
#pragma unroll
    for (int j = 0; j < 32; j++) ss = fmaf(xs[j], xs[j], ss);
    ss += __shfl_xor(ss, 32, 64);   // both halves now hold the row total
    float inv = 1.0f / fmaxf(sqrtf(ss), 1e-12f);
    if (h == 0) ginv[row] = 16384.0f * inv;  // pow2 scale: exact ratio later
#pragma unroll
    for (int cc = 0; cc < 2; cc++) {
      int c = h * 2 + cc;   // this lane holds kchunks 2h, 2h+1 fully
      size_t s0 = ((size_t)(tile * 4 + c) * 64 + r) * 8;        // j 0..7
      size_t s1 = ((size_t)(tile * 4 + c) * 64 + r + 32) * 8;   // j 8..15
      ushort8 hh, ll;
#pragma unroll
      for (int j = 0; j < 8; j++) {
        float xn = xs[cc * 16 + j] * inv;
        unsigned short hj = bf16rn(xn);
        hh[j] = hj;
        ll[j] = bf16rn(xn - bf2f(hj));
      }
      *(ushort8*)(dh + s0) = hh;
      *(ushort8*)(dl + s0) = ll;
#pragma unroll
      for (int j = 0; j < 8; j++) {
        float xn = xs[cc * 16 + 8 + j] * inv;
        unsigned short hj = bf16rn(xn);
        hh[j] = hj;
        ll[j] = bf16rn(xn - bf2f(hj));
      }
      *(ushort8*)(dh + s1) = hh;
      *(ushort8*)(dl + s1) = ll;
    }
  }
}

// ===== kernel 2: 32x32x16 MFMA KNN candidate generation (KNN1+KNN2) =====
// Wave = 32 queries x 32 keys/tile. A = keys, B = queries -> C/D (verified):
// query = col = lane&31, key row = (reg&3)+8*(reg>>2)+4*(lane>>5).
// 12 chained MFMAs/tile (4 kchunks x {hh, h*lo_q, lo_k*h}). Key bytes per
// (q,k) pair HALVED vs 16x16 (R14: L2 traffic ~46us was the co-bottleneck).
// Lane owns one query: single tv[8]; 1 butterfly round (m=32). q-frags pinned
// in AGPRs (R14). Merges re-rank exact fp32 (R6); explicit mask (R9).
__global__ __launch_bounds__(256)
void k_knn(const unsigned short* __restrict__ vfh, const unsigned short* __restrict__ vfl,
           const unsigned short* __restrict__ pfh, const unsigned short* __restrict__ pfl,
           const float* __restrict__ vm,
           unsigned* __restrict__ pc1, unsigned* __restrict__ pc2) {
  int wid = (blockIdx.x * 256 + threadIdx.x) >> 6;
  int lane = threadIdx.x & 63, col = lane & 31, h = lane >> 5;

  const unsigned short *KH, *KL;
  const float* mask;
  unsigned* PC;
  int qt_g, kb0, ntiles, tbase, row0;
  if (wid < QT32 * NC1) {  // KNN1: keys = pf (128 tiles32/batch)
    int ck = wid & 3;
    qt_g = wid >> 2;
    int batch = qt_g >> 6;
    KH = pfh; KL = pfl;
    mask = nullptr;
    ntiles = 32;
    kb0 = ck * 32;
    tbase = batch * 128;
    PC = pc1;
    row0 = ck * 8;
  } else {                 // KNN2: keys = vf (64 tiles32/batch), visible only
    int w = wid - QT32 * NC1;
    int ck = w & 3;
    qt_g = w >> 2;
    int batch = qt_g >> 6;
    KH = vfh; KL = vfl;
    mask = vm + batch * NVV;
    ntiles = 16;
    kb0 = ck * 16;
    tbase = batch * 64;
    PC = pc2;
    row0 = ck * 8;
  }

  size_t qb = (size_t)qt_g * 2048 + lane * 8;
  short8 qh0 = *(const short8*)(vfh + qb);
  short8 qh1 = *(const short8*)(vfh + qb + 512);
  short8 qh2 = *(const short8*)(vfh + qb + 1024);
  short8 qh3 = *(const short8*)(vfh + qb + 1536);
  short8 ql0 = *(const short8*)(vfl + qb);
  short8 ql1 = *(const short8*)(vfl + qb + 512);
  short8 ql2 = *(const short8*)(vfl + qb + 1024);
  short8 ql3 = *(const short8*)(vfl + qb + 1536);
  // AGPR homes are free for MFMA A/B operands (R14); frees VGPRs for tv/keys.
  asm volatile("" : "+a"(qh0), "+a"(qh1), "+a"(qh2), "+a"(qh3),
                    "+a"(ql0), "+a"(ql1), "+a"(ql2), "+a"(ql3));

  unsigned tv[8];
#pragma unroll
  for (int k = 0; k < 8; k++) tv[k] = 0u;

#pragma unroll 2
  for (int kt = 0; kt < ntiles; kt++) {
    size_t bo = (size_t)(tbase + kb0 + kt) * 2048 + lane * 8;
    short8 kh0 = *(const short8*)(KH + bo);
    short8 kh1 = *(const short8*)(KH + bo + 512);
    short8 kh2 = *(const short8*)(KH + bo + 1024);
    short8 kh3 = *(const short8*)(KH + bo + 1536);
    short8 kl0 = *(const short8*)(KL + bo);
    short8 kl1 = *(const short8*)(KL + bo + 512);
    short8 kl2 = *(const short8*)(KL + bo + 1024);
    short8 kl3 = *(const short8*)(KL + bo + 1536);
    int base32 = (kb0 + kt) * 32;
    f32x16 acc = {0.f};
    acc = __builtin_amdgcn_mfma_f32_32x32x16_bf16(kh0, qh0, acc, 0, 0, 0);
    acc = __builtin_amdgcn_mfma_f32_32x32x16_bf16(kh1, qh1, acc, 0, 0, 0);
    acc = __builtin_amdgcn_mfma_f32_32x32x16_bf16(kh2, qh2, acc, 0, 0, 0);
    acc = __builtin_amdgcn_mfma_f32_32x32x16_bf16(kh3, qh3, acc, 0, 0, 0);
    acc = __builtin_amdgcn_mfma_f32_32x32x16_bf16(kh0, ql0, acc, 0, 0, 0);
    acc = __builtin_amdgcn_mfma_f32_32x32x16_bf16(kh1, ql1, acc, 0, 0, 0);
    acc = __builtin_amdgcn_mfma_f32_32x32x16_bf16(kh2, ql2, acc, 0, 0, 0);
    acc = __builtin_amdgcn_mfma_f32_32x32x16_bf16(kh3, ql3, acc, 0, 0, 0);
    acc = __builtin_amdgcn_mfma_f32_32x32x16_bf16(kl0, qh0, acc, 0, 0, 0);
    acc = __builtin_amdgcn_mfma_f32_32x32x16_bf16(kl1, qh1, acc, 0, 0, 0);
    acc = __builtin_amdgcn_mfma_f32_32x32x16_bf16(kl2, qh2, acc, 0, 0, 0);
    acc = __builtin_amdgcn_mfma_f32_32x32x16_bf16(kl3, qh3, acc, 0, 0, 0);
#pragma unroll
    for (int g = 0; g < 4; g++) {
      float4 mv;
      if (mask) mv = *(const float4*)(mask + base32 + g * 8 + 4 * h);
#pragma unroll
      for (int rr = 0; rr < 4; rr++) {
        int reg = g * 4 + rr;
        int key = base32 + g * 8 + 4 * h + rr;  // row=(reg&3)+8*(reg>>2)+4h
        float s = acc[reg];
        unsigned u = (unsigned)fmaxf(fmaf(s, 520000.0f, 520000.0f), 0.0f);
        unsigned pk = (u << 12) | (unsigned)key;
        if (mask) {
          float mr = (rr == 0) ? mv.x : (rr == 1) ? mv.y : (rr == 2) ? mv.z : mv.w;
          pk = (mr >= 0.5f) ? pk : 0u;
        }
        net8(tv, pk);
      }
    }
  }

  // single butterfly round: lane^32 holds the other 16 key-rows of same query
  {
    unsigned ov[8];
#pragma unroll
    for (int k = 0; k < 8; k++) ov[k] = (unsigned)__shfl_xor((int)tv[k], 32, 64);
#pragma unroll
    for (int k = 7; k >= 0; k--) net8(tv, ov[k]);
  }

  if (h == 0) {
    int q = qt_g * 32 + col;
#pragma unroll
    for (int k = 0; k < 8; k++)
      PC[(size_t)(row0 + k) * NQ + q] = tv[k];
  }
}

__device__ __forceinline__ float dot64(const float4* __restrict__ a,
                                       const float4* __restrict__ b) {
  float a0 = 0.f, a1 = 0.f, a2 = 0.f, a3 = 0.f;
#pragma unroll
  for (int c = 0; c < 16; c++) {
    float4 x = a[c], y = b[c];
    a0 = fmaf(x.x, y.x, a0);
    a1 = fmaf(x.y, y.y, a1);
    a2 = fmaf(x.z, y.z, a2);
    a3 = fmaf(x.w, y.w, a3);
  }
  return (a0 + a1) + (a2 + a3);
}

// ===== kernel 3: exact re-rank of 32 KNN1 candidates + flow_init (32 lanes/q) =====
__global__ __launch_bounds__(256) void k_merge_flow(const unsigned* __restrict__ pc,
                                                    const float* __restrict__ vf,
                                                    const float* __restrict__ pf,
                                                    const float* __restrict__ pts,
                                                    const float* __restrict__ vtx,
                                                    const float* __restrict__ inv_pf_s,
                                                    float* __restrict__ flow_ws,
                                                    float* __restrict__ out) {
  int T = blockIdx.x * 256 + threadIdx.x;
  int q = T >> 5, c = T & 31, batch = q >> 11;
  const float4* qp = (const float4*)(vf + (size_t)q * DD);
  float tv[8];
  int ti[8];
#pragma unroll
  for (int k = 0; k < 8; k++) { tv[k] = -3.0e38f; ti[k] = 0; }
  {  // 32 candidate rows / 32 lanes
    unsigned pk = pc[(size_t)c * NQ + q];
    if (pk > 0xFFFu) {
      int id = (int)(pk & 0xFFFu);
      int prow = batch * NPP + id;
      float s = dot64(qp, (const float4*)(pf + (size_t)prow * DD)) *
                inv_pf_s[prow] * 6.103515625e-5f;  // * 2^-14 (exact)
      ins8(tv, ti, s, id);
    }
  }
#pragma unroll
  for (int m = 1; m <= 16; m <<= 1) {
    float ov[8];
    int oi[8];
#pragma unroll
    for (int k = 0; k < 8; k++) {
      ov[k] = __shfl_xor(tv[k], m, 64);
      oi[k] = __shfl_xor(ti[k], m, 64);
    }
#pragma unroll
    for (int k = 7; k >= 0; k--)
      if (ov[k] > tv[0]) ins8(tv, ti, ov[k], oi[k]);
  }
  int id = ti[0];
  float sv = tv[0];
#pragma unroll
  for (int k = 1; k < 8; k++) {
    id = (c == k) ? ti[k] : id;
    sv = (c == k) ? tv[k] : sv;
  }

  float ax = 0.f, ay = 0.f, az = 0.f, den = 0.f;
  if (c < 8) {
    int prow = batch * NPP + id;
    float w = sv * 16384.0f / inv_pf_s[prow];  // = raw dot (exact pow2 ratio)
    ax = (pts[prow * 3 + 0] - vtx[q * 3 + 0]) * w;
    ay = (pts[prow * 3 + 1] - vtx[q * 3 + 1]) * w;
    az = (pts[prow * 3 + 2] - vtx[q * 3 + 2]) * w;
    den = w;
  }
#pragma unroll
  for (int m = 1; m <= 16; m <<= 1) {
    ax += __shfl_xor(ax, m, 64);
    ay += __shfl_xor(ay, m, 64);
    az += __shfl_xor(az, m, 64);
    den += __shfl_xor(den, m, 64);
  }
  if (c == 0) {
    float fx = ax / den, fy = ay / den, fz = az / den;
    flow_ws[q * 4 + 0] = fx;
    flow_ws[q * 4 + 1] = fy;
    flow_ws[q * 4 + 2] = fz;
    out[q * 4 + 0] = fx;
    out[q * 4 + 1] = fy;
    out[q * 4 + 2] = fz;
  }
}

// ===== kernel 4: exact re-rank of 32 KNN2 candidates + interpolate invisible =====
__global__ __launch_bounds__(256) void k_merge_final(const unsigned* __restrict__ pc,
                                                     const float* __restrict__ vf,
                                                     const float* __restrict__ vm,
                                                     const float* __restrict__ inv_vf_s,
                                                     const float* __restrict__ flow_ws,
                                                     float* __restrict__ out) {
  int T = blockIdx.x * 256 + threadIdx.x;
  int q = T >> 5, c = T & 31, batch = q >> 11;
  if (vm[q] >= 0.5f) return;
  const float4* qp = (const float4*)(vf + (size_t)q * DD);
  float tv[8];
  int ti[8];
#pragma unroll
  for (int k = 0; k < 8; k++) { tv[k] = -3.0e38f; ti[k] = 0; }
  {  // 32 candidate rows / 32 lanes; pk <= 0xFFF = masked sentinel
    unsigned pk = pc[(size_t)c * NQ + q];
    if (pk > 0xFFFu) {
      int id = (int)(pk & 0xFFFu);
      int krow = batch * NVV + id;
      float s = dot64(qp, (const float4*)(vf + (size_t)krow * DD)) *
                inv_vf_s[krow] * 6.103515625e-5f;
      ins8(tv, ti, s, id);
    }
  }
#pragma unroll
  for (int m = 1; m <= 16; m <<= 1) {
    float ov[8];
    int oi[8];
#pragma unroll
    for (int k = 0; k < 8; k++) {
      ov[k] = __shfl_xor(tv[k], m, 64);
      oi[k] = __shfl_xor(ti[k], m, 64);
    }
#pragma unroll
    for (int k = 7; k >= 0; k--)
      if (ov[k] > tv[0]) ins8(tv, ti, ov[k], oi[k]);
  }
  int id = ti[0];
  float sv = tv[0];
#pragma unroll
  for (int k = 1; k < 8; k++) {
    id = (c == k) ? ti[k] : id;
    sv = (c == k) ? tv[k] : sv;
  }

  float ax = 0.f, ay = 0.f, az = 0.f, den = 0.f;
  if (c < 8) {
    int krow = batch * NVV + id;
    float w = sv * 16384.0f / inv_vf_s[krow];
    ax = flow_ws[krow * 4 + 0] * w;
    ay = flow_ws[krow * 4 + 1] * w;
    az = flow_ws[krow * 4 + 2] * w;
    den = w;
  }
#pragma unroll
  for (int m = 1; m <= 16; m <<= 1) {
    ax += __shfl_xor(ax, m, 64);
    ay += __shfl_xor(ay, m, 64);
    az += __shfl_xor(az, m, 64);
    den += __shfl_xor(den, m, 64);
  }
  if (c == 0) {
    out[q * 4 + 0] = ax / den;
    out[q * 4 + 1] = ay / den;
    out[q * 4 + 2] = az / den;
  }
}

extern "C" void kernel_launch(void* const* d_in, const int* in_sizes, int n_in,
                              void* d_out, int out_size, void* d_ws, size_t ws_size,
                              hipStream_t stream) {
  const float* vtx = (const float*)d_in[0];
  const float* pts = (const float*)d_in[1];
  const float* vf = (const float*)d_in[2];
  const float* pf = (const float*)d_in[3];
  const float* lg = (const float*)d_in[4];
  float* out = (float*)d_out;
  float* ws = (float*)d_ws;

  float* vm = ws;
  float* inv_vf_s = ws + 16384;
  float* inv_pf_s = ws + 32768;
  float* flow = ws + 65536;
  unsigned* pc1 = (unsigned*)(ws + 131072);
  unsigned* pc2 = (unsigned*)(ws + 655360);
  unsigned short* vfh = (unsigned short*)(ws + 1179648);
  unsigned short* vfl = (unsigned short*)(ws + 1703936);   // +524288 floats
  unsigned short* pfh = (unsigned short*)(ws + 2228224);   // +524288
  unsigned short* pfl = (unsigned short*)(ws + 3276800);   // +1048576

  k_prep<<<BB + (QT32 + PT32) / 4, 256, 0, stream>>>(lg, vf, pf, vm, inv_vf_s,
                                                     inv_pf_s, vfh, vfl, pfh, pfl, out);
  k_knn<<<(QT32 * NC1 + QT32 * NC2) / 4, 256, 0, stream>>>(vfh, vfl, pfh, pfl,
                                                           vm, pc1, pc2);
  k_merge_flow<<<NQ * 32 / 256, 256, 0, stream>>>(pc1, vf, pf, pts, vtx,
                                                  inv_pf_s, flow, out);
  k_merge_final<<<NQ * 32 / 256, 256, 0, stream>>>(pc2, vf, vm, inv_vf_s, flow, out);
}